// Round 8
// baseline (245.121 us; speedup 1.0000x reference)
//
#include <hip/hip_runtime.h>

#define C_IN   512
#define C_INT  128
#define NBUCK  1024

typedef short short8 __attribute__((ext_vector_type(8)));
typedef float floatx4 __attribute__((ext_vector_type(4)));

// ---------- helpers ----------

// Monotone (after clamp) bucket mapping; identical everywhere it is used.
__device__ __forceinline__ int bucket_of(float v, float bmin, float inv_w) {
    float fk = (v - bmin) * inv_w;
    fk = fminf(fmaxf(fk, 0.f), (float)(NBUCK - 1));
    return (int)fk;
}

// fp32 -> bf16 round-to-nearest-even
__device__ __forceinline__ short bf16rnd(float v) {
    unsigned u = __float_as_uint(v);
    return (short)((u + 0x7fffu + ((u >> 16) & 1u)) >> 16);
}

// ---------- K1: prep (verified r5, unchanged) ----------
// blocks 0..7: ut; 8..15: up; 16: scal = {s0, s1, bmin, inv_w}; 17..24: WgT.

__global__ __launch_bounds__(256) void prep_kernel(
        const float* __restrict__ Wt, const float* __restrict__ Wp,
        const float* __restrict__ Wg, const float* __restrict__ wcat,
        const float* __restrict__ bt, const float* __restrict__ bp,
        float* __restrict__ ut, float* __restrict__ up, float* __restrict__ scal,
        unsigned short* __restrict__ WgT) {
    int t = threadIdx.x, bk = blockIdx.x;
    if (bk < 16) {
        const float* W  = (bk < 8) ? Wt : Wp;
        const float* wv = wcat + ((bk < 8) ? 0 : C_INT);
        float* dst      = (bk < 8) ? ut : up;
        int k = (bk & 7) * 64 + (t >> 2);
        int q = t & 3;
        const float4* row = (const float4*)(W + (size_t)k * C_INT);
        const float4* cv4 = (const float4*)wv;
        float s = 0.f;
        #pragma unroll
        for (int i = 0; i < 8; ++i) {
            float4 a = row[q * 8 + i];
            float4 c = cv4[q * 8 + i];
            s += a.x * c.x + a.y * c.y + a.z * c.z + a.w * c.w;
        }
        s += __shfl_xor(s, 1);
        s += __shfl_xor(s, 2);
        if (q == 0) dst[k] = s;
    } else if (bk == 16) {
        float sumsq = 0.f;
        const float4* w2v = (const float4*)(wcat + C_INT);
        for (int r = 0; r < 2; ++r) {
            int k = t * 2 + r;
            const float4* row = (const float4*)(Wp + (size_t)k * C_INT);
            float d = 0.f;
            #pragma unroll
            for (int i = 0; i < 32; ++i) {
                float4 a4 = row[i]; float4 c4 = w2v[i];
                d += a4.x * c4.x + a4.y * c4.y + a4.z * c4.z + a4.w * c4.w;
            }
            sumsq += d * d;
        }
        float s1p = (t < C_INT) ? bt[t] * wcat[t] : 0.f;
        float s2p = (t < C_INT) ? bp[t] * wcat[C_INT + t] : 0.f;
        for (int off = 32; off; off >>= 1) {
            s1p   += __shfl_down(s1p, off);
            s2p   += __shfl_down(s2p, off);
            sumsq += __shfl_down(sumsq, off);
        }
        __shared__ float red[12];
        int w = t >> 6, lane = t & 63;
        if (lane == 0) { red[w] = s1p; red[4 + w] = s2p; red[8 + w] = sumsq; }
        __syncthreads();
        if (t == 0) {
            float s0 = red[0] + red[1] + red[2] + red[3];
            float s1 = red[4] + red[5] + red[6] + red[7];
            float sq = red[8] + red[9] + red[10] + red[11];
            float sigma = sqrtf(sq);
            scal[0] = s0; scal[1] = s1;
            if (sigma > 1e-20f) {
                scal[2] = s1 - 8.f * sigma;                  // bmin
                scal[3] = (float)NBUCK / (16.f * sigma);     // inv_w
            } else {
                scal[2] = s1 - 1.f; scal[3] = 0.f;           // degenerate
            }
        }
    } else {
        __shared__ float tile[64][132];
        int kb = (bk - 17) * 64;
        #pragma unroll
        for (int it = 0; it < 8; ++it) {
            int idx = it * 256 + t;
            int r = idx >> 5, c4 = idx & 31;
            *(float4*)&tile[r][c4 * 4] =
                ((const float4*)(Wg + (size_t)(kb + r) * C_INT))[c4];
        }
        __syncthreads();
        int n = t & 127, kc = (t >> 7) * 32;
        unsigned pk[16];
        #pragma unroll
        for (int i = 0; i < 16; ++i) {
            unsigned lo = (unsigned short)bf16rnd(tile[kc + 2 * i][n]);
            unsigned hi = (unsigned short)bf16rnd(tile[kc + 2 * i + 1][n]);
            pk[i] = lo | (hi << 16);
        }
        uint4* dst = (uint4*)(WgT + (size_t)n * C_IN + kb + kc);
        #pragma unroll
        for (int i2 = 0; i2 < 4; ++i2) dst[i2] = *(uint4*)&pk[i2 * 4];
    }
}

// ---------- K2: MFMA gemm, 4 waves/block K-split (verified r7, unchanged) ----------

#define RSTR 66

__global__ __launch_bounds__(256) void gemm_mfma(
        const float* __restrict__ x, const unsigned short* __restrict__ WgT,
        const float* __restrict__ bg,
        const float* __restrict__ ut, const float* __restrict__ up,
        const float* __restrict__ scal,
        _Float16* __restrict__ g, float* __restrict__ a, float* __restrict__ b) {
    __shared__ float red[3][36][RSTR];
    int tid = threadIdx.x;
    int lane = tid & 63, wv = tid >> 6;
    int i0 = blockIdx.x * 16;
    int m = lane & 15, q = lane >> 4;
    floatx4 accg[8] = {};
    floatx4 accab = {};
    const float* xrow = x + (size_t)(i0 + m) * C_IN + q * 8;
    const float* absrc = (m == 0) ? ut : up;
    #pragma unroll
    for (int ks = 0; ks < 4; ++ks) {
        int k0 = (wv * 4 + ks) * 32;
        float4 f0 = *(const float4*)(xrow + k0);
        float4 f1 = *(const float4*)(xrow + k0 + 4);
        short8 af;
        af[0] = bf16rnd(f0.x); af[1] = bf16rnd(f0.y);
        af[2] = bf16rnd(f0.z); af[3] = bf16rnd(f0.w);
        af[4] = bf16rnd(f1.x); af[5] = bf16rnd(f1.y);
        af[6] = bf16rnd(f1.z); af[7] = bf16rnd(f1.w);
        short8 abf = {};
        if (m < 2) {
            float4 u0 = *(const float4*)(absrc + k0 + q * 8);
            float4 u1 = *(const float4*)(absrc + k0 + q * 8 + 4);
            abf[0] = bf16rnd(u0.x); abf[1] = bf16rnd(u0.y);
            abf[2] = bf16rnd(u0.z); abf[3] = bf16rnd(u0.w);
            abf[4] = bf16rnd(u1.x); abf[5] = bf16rnd(u1.y);
            abf[6] = bf16rnd(u1.z); abf[7] = bf16rnd(u1.w);
        }
        accab = __builtin_amdgcn_mfma_f32_16x16x32_bf16(af, abf, accab, 0, 0, 0);
        #pragma unroll
        for (int f = 0; f < 8; ++f) {
            short8 bfr = *(const short8*)(WgT + (size_t)(f * 16 + m) * C_IN + k0 + q * 8);
            accg[f] = __builtin_amdgcn_mfma_f32_16x16x32_bf16(af, bfr, accg[f], 0, 0, 0);
        }
    }
    if (wv) {
        #pragma unroll
        for (int f = 0; f < 8; ++f)
            #pragma unroll
            for (int r = 0; r < 4; ++r)
                red[wv - 1][f * 4 + r][lane] = accg[f][r];
        #pragma unroll
        for (int r = 0; r < 4; ++r)
            red[wv - 1][32 + r][lane] = accab[r];
    }
    __syncthreads();
    if (wv == 0) {
        #pragma unroll
        for (int w = 0; w < 3; ++w) {
            #pragma unroll
            for (int f = 0; f < 8; ++f)
                #pragma unroll
                for (int r = 0; r < 4; ++r)
                    accg[f][r] += red[w][f * 4 + r][lane];
            #pragma unroll
            for (int r = 0; r < 4; ++r)
                accab[r] += red[w][32 + r][lane];
        }
        #pragma unroll
        for (int f = 0; f < 8; ++f) {
            int col = f * 16 + m;
            float bgv = bg[col];
            #pragma unroll
            for (int r = 0; r < 4; ++r) {
                int row = i0 + q * 4 + r;
                g[(size_t)row * C_INT + col] = (_Float16)(accg[f][r] + bgv);
            }
        }
        if (m < 2) {
            float off = m ? scal[1] : scal[0];
            float* dst = m ? b : a;
            #pragma unroll
            for (int r = 0; r < 4; ++r) dst[i0 + q * 4 + r] = accab[r] + off;
        }
    }
}

// ---------- K3: fused post kernel: sort + bucket sums + suffix + out ----------
// 128 blocks (one per channel) x 1024 threads. LDS = exactly 64 KB with
// phase-disjoint aliasing of scan temps onto dead regions.

__global__ __launch_bounds__(1024, 4) void post_kernel(
        const _Float16* __restrict__ g, const float* __restrict__ a,
        const float* __restrict__ b, const float* __restrict__ scal,
        float* __restrict__ out, float inv_n) {
    __shared__ __align__(16) unsigned char smem[65536];
    float*          bs  = (float*)smem;                       // [8192] sorted b
    unsigned short* ls  = (unsigned short*)(smem + 32768);    // [8192] sorted row idx
    unsigned*       oh  = (unsigned*)(smem + 49152);          // [1024] hist->incl scan
    unsigned*       cur = (unsigned*)(smem + 53248);          // [1024] cursors
    float*          P1  = (float*)(smem + 57344);             // [1024] suffix sums
    float*          P2  = (float*)(smem + 61440);             // [1024]
    unsigned* wtu = (unsigned*)(smem + 57344);                // alias P1 (dead in phase 3)
    float*    wt1 = (float*)(smem + 53248);                   // alias cur (dead after scatter)
    float*    wt2 = (float*)(smem + 53248 + 64);

    int t = threadIdx.x, c = blockIdx.x;
    int lane = t & 63, wv = t >> 6;
    float bmin = scal[2], inv_w = scal[3];

    oh[t] = 0u; cur[t] = 0u;
    __syncthreads();

    // phase 1: histogram (b read coalesced from global, values kept in regs)
    int kb[8];
    float bv[8];
    #pragma unroll
    for (int r = 0; r < 8; ++r) {
        int j = t + r * 1024;
        bv[r] = b[j];
        kb[r] = bucket_of(bv[r], bmin, inv_w);
        atomicAdd(&oh[kb[r]], 1u);
    }
    __syncthreads();

    // phase 2: inclusive scan of oh (shfl, 2-level; temps alias P1)
    unsigned v = oh[t];
    #pragma unroll
    for (int d = 1; d < 64; d <<= 1) {
        unsigned u = __shfl_up(v, d);
        if (lane >= d) v += u;
    }
    if (lane == 63) wtu[wv] = v;
    __syncthreads();
    if (t < 16) {
        unsigned w = wtu[t];
        #pragma unroll
        for (int d = 1; d < 16; d <<= 1) {
            unsigned u = __shfl_up(w, d);
            if (t >= d) w += u;
        }
        wtu[t] = w;
    }
    __syncthreads();
    if (wv) v += wtu[wv - 1];
    oh[t] = v;
    __syncthreads();

    // phase 3: scatter row idx + b value into sorted order
    #pragma unroll
    for (int r = 0; r < 8; ++r) {
        int j = t + r * 1024;
        int k = kb[r];
        unsigned st = k ? oh[k - 1] : 0u;
        unsigned pos = atomicAdd(&cur[k], 1u);
        ls[st + pos] = (unsigned short)j;
        bs[st + pos] = bv[r];
    }
    __syncthreads();

    // phase 4: per-bucket sums for channel c (thread t = bucket t)
    unsigned e0 = t ? oh[t - 1] : 0u, e1 = oh[t];
    float h1 = 0.f, h2 = 0.f;
    for (unsigned e = e0; e < e1; ++e) {
        int j = ls[e];
        float gv = (float)g[(size_t)j * C_INT + c];
        h1 += gv; h2 += bs[e] * gv;
    }
    // phase 5: inclusive scan of (h1,h2) -> suffix sums (temps alias cur)
    float v1 = h1, v2 = h2;
    #pragma unroll
    for (int d = 1; d < 64; d <<= 1) {
        float u1 = __shfl_up(v1, d), u2 = __shfl_up(v2, d);
        if (lane >= d) { v1 += u1; v2 += u2; }
    }
    if (lane == 63) { wt1[wv] = v1; wt2[wv] = v2; }
    __syncthreads();
    if (t < 16) {
        float w1 = wt1[t], w2 = wt2[t];
        #pragma unroll
        for (int d = 1; d < 16; d <<= 1) {
            float u1 = __shfl_up(w1, d), u2 = __shfl_up(w2, d);
            if (t >= d) { w1 += u1; w2 += u2; }
        }
        wt1[t] = w1; wt2[t] = w2;
    }
    __syncthreads();
    if (wv) { v1 += wt1[wv - 1]; v2 += wt2[wv - 1]; }
    float tot1 = wt1[15], tot2 = wt2[15];
    __syncthreads();               // wt* reads done before P1/P2 (aliased region is distinct; oh/cur region reuse barrier)
    P1[t] = tot1 - v1 + h1;        // sum over buckets >= t
    P2[t] = tot2 - v2 + h2;
    __syncthreads();

    // phase 6: per-row output for channel c (8 rows per thread, coalesced a-reads)
    #pragma unroll
    for (int r = 0; r < 8; ++r) {
        int i = t + r * 1024;
        float ai = a[i], thr = -ai;
        int ki = bucket_of(thr, bmin, inv_w);
        float acc = (ki + 1 < NBUCK) ? (ai * P1[ki + 1] + P2[ki + 1]) : 0.f;
        unsigned f0 = ki ? oh[ki - 1] : 0u, f1 = oh[ki];
        for (unsigned e = f0; e < f1; ++e) {
            float bj = bs[e];
            if (bj > thr)
                acc += (ai + bj) * (float)g[(size_t)ls[e] * C_INT + c];
        }
        out[(size_t)i * C_INT + c] = acc * inv_n;
    }
}

// ---------- launch ----------

extern "C" void kernel_launch(void* const* d_in, const int* in_sizes, int n_in,
                              void* d_out, int out_size, void* d_ws, size_t ws_size,
                              hipStream_t stream) {
    const float* x    = (const float*)d_in[0];
    const float* Wg   = (const float*)d_in[1];
    const float* bg   = (const float*)d_in[2];
    const float* Wt   = (const float*)d_in[3];
    const float* bt   = (const float*)d_in[4];
    const float* Wp   = (const float*)d_in[5];
    const float* bp   = (const float*)d_in[6];
    const float* wcat = (const float*)d_in[7];
    float* out = (float*)d_out;
    int n = in_sizes[0] / C_IN;   // 8192

    char* w = (char*)d_ws;
    size_t off = 0;
    auto alloc = [&](size_t bytes) -> void* {
        void* p = w + off;
        off += (bytes + 255) & ~(size_t)255;
        return p;
    };
    float*          ut   = (float*)alloc(C_IN * 4);
    float*          up   = (float*)alloc(C_IN * 4);
    float*          scal = (float*)alloc(16);
    float*          a    = (float*)alloc((size_t)n * 4);
    float*          b    = (float*)alloc((size_t)n * 4);
    _Float16*       g    = (_Float16*)alloc((size_t)n * C_INT * 2);
    unsigned short* WgT  = (unsigned short*)alloc((size_t)C_INT * C_IN * 2);

    prep_kernel<<<25, 256, 0, stream>>>(Wt, Wp, Wg, wcat, bt, bp, ut, up, scal, WgT);
    gemm_mfma<<<n / 16, 256, 0, stream>>>(x, WgT, bg, ut, up, scal, g, a, b);
    post_kernel<<<C_INT, 1024, 0, stream>>>(g, a, b, scal, out, 1.0f / (float)n);
}

// Round 9
// 180.322 us; speedup vs baseline: 1.3593x; 1.3593x over previous
//
#include <hip/hip_runtime.h>

#define C_IN   512
#define C_INT  128
#define NBUCK  8192
#define SEG    128
#define NSEG   64    // 8192 / SEG

typedef short short8 __attribute__((ext_vector_type(8)));
typedef float floatx4 __attribute__((ext_vector_type(4)));

// ---------- helpers ----------

// Monotone (after clamp) bucket mapping; identical everywhere it is used.
__device__ __forceinline__ int bucket_of(float v, float bmin, float inv_w) {
    float fk = (v - bmin) * inv_w;
    fk = fminf(fmaxf(fk, 0.f), (float)(NBUCK - 1));
    return (int)fk;
}

// fp32 -> bf16 round-to-nearest-even
__device__ __forceinline__ short bf16rnd(float v) {
    unsigned u = __float_as_uint(v);
    return (short)((u + 0x7fffu + ((u >> 16) & 1u)) >> 16);
}

// ---------- K1: prep (verified r5, unchanged) ----------

__global__ __launch_bounds__(256) void prep_kernel(
        const float* __restrict__ Wt, const float* __restrict__ Wp,
        const float* __restrict__ Wg, const float* __restrict__ wcat,
        const float* __restrict__ bt, const float* __restrict__ bp,
        float* __restrict__ ut, float* __restrict__ up, float* __restrict__ scal,
        unsigned short* __restrict__ WgT) {
    int t = threadIdx.x, bk = blockIdx.x;
    if (bk < 16) {
        const float* W  = (bk < 8) ? Wt : Wp;
        const float* wv = wcat + ((bk < 8) ? 0 : C_INT);
        float* dst      = (bk < 8) ? ut : up;
        int k = (bk & 7) * 64 + (t >> 2);
        int q = t & 3;
        const float4* row = (const float4*)(W + (size_t)k * C_INT);
        const float4* cv4 = (const float4*)wv;
        float s = 0.f;
        #pragma unroll
        for (int i = 0; i < 8; ++i) {
            float4 a = row[q * 8 + i];
            float4 c = cv4[q * 8 + i];
            s += a.x * c.x + a.y * c.y + a.z * c.z + a.w * c.w;
        }
        s += __shfl_xor(s, 1);
        s += __shfl_xor(s, 2);
        if (q == 0) dst[k] = s;
    } else if (bk == 16) {
        float sumsq = 0.f;
        const float4* w2v = (const float4*)(wcat + C_INT);
        for (int r = 0; r < 2; ++r) {
            int k = t * 2 + r;
            const float4* row = (const float4*)(Wp + (size_t)k * C_INT);
            float d = 0.f;
            #pragma unroll
            for (int i = 0; i < 32; ++i) {
                float4 a4 = row[i]; float4 c4 = w2v[i];
                d += a4.x * c4.x + a4.y * c4.y + a4.z * c4.z + a4.w * c4.w;
            }
            sumsq += d * d;
        }
        float s1p = (t < C_INT) ? bt[t] * wcat[t] : 0.f;
        float s2p = (t < C_INT) ? bp[t] * wcat[C_INT + t] : 0.f;
        for (int off = 32; off; off >>= 1) {
            s1p   += __shfl_down(s1p, off);
            s2p   += __shfl_down(s2p, off);
            sumsq += __shfl_down(sumsq, off);
        }
        __shared__ float red[12];
        int w = t >> 6, lane = t & 63;
        if (lane == 0) { red[w] = s1p; red[4 + w] = s2p; red[8 + w] = sumsq; }
        __syncthreads();
        if (t == 0) {
            float s0 = red[0] + red[1] + red[2] + red[3];
            float s1 = red[4] + red[5] + red[6] + red[7];
            float sq = red[8] + red[9] + red[10] + red[11];
            float sigma = sqrtf(sq);
            scal[0] = s0; scal[1] = s1;
            if (sigma > 1e-20f) {
                scal[2] = s1 - 8.f * sigma;                  // bmin
                scal[3] = (float)NBUCK / (16.f * sigma);     // inv_w
            } else {
                scal[2] = s1 - 1.f; scal[3] = 0.f;           // degenerate
            }
        }
    } else {
        __shared__ float tile[64][132];
        int kb = (bk - 17) * 64;
        #pragma unroll
        for (int it = 0; it < 8; ++it) {
            int idx = it * 256 + t;
            int r = idx >> 5, c4 = idx & 31;
            *(float4*)&tile[r][c4 * 4] =
                ((const float4*)(Wg + (size_t)(kb + r) * C_INT))[c4];
        }
        __syncthreads();
        int n = t & 127, kc = (t >> 7) * 32;
        unsigned pk[16];
        #pragma unroll
        for (int i = 0; i < 16; ++i) {
            unsigned lo = (unsigned short)bf16rnd(tile[kc + 2 * i][n]);
            unsigned hi = (unsigned short)bf16rnd(tile[kc + 2 * i + 1][n]);
            pk[i] = lo | (hi << 16);
        }
        uint4* dst = (uint4*)(WgT + (size_t)n * C_IN + kb + kc);
        #pragma unroll
        for (int i2 = 0; i2 < 4; ++i2) dst[i2] = *(uint4*)&pk[i2 * 4];
    }
}

// ---------- K2: MFMA gemm, 4 waves/block K-split (verified r7, unchanged) ----------

#define RSTR 66

__global__ __launch_bounds__(256) void gemm_mfma(
        const float* __restrict__ x, const unsigned short* __restrict__ WgT,
        const float* __restrict__ bg,
        const float* __restrict__ ut, const float* __restrict__ up,
        const float* __restrict__ scal,
        _Float16* __restrict__ g, float* __restrict__ a, float* __restrict__ b) {
    __shared__ float red[3][36][RSTR];
    int tid = threadIdx.x;
    int lane = tid & 63, wv = tid >> 6;
    int i0 = blockIdx.x * 16;
    int m = lane & 15, q = lane >> 4;
    floatx4 accg[8] = {};
    floatx4 accab = {};
    const float* xrow = x + (size_t)(i0 + m) * C_IN + q * 8;
    const float* absrc = (m == 0) ? ut : up;
    #pragma unroll
    for (int ks = 0; ks < 4; ++ks) {
        int k0 = (wv * 4 + ks) * 32;
        float4 f0 = *(const float4*)(xrow + k0);
        float4 f1 = *(const float4*)(xrow + k0 + 4);
        short8 af;
        af[0] = bf16rnd(f0.x); af[1] = bf16rnd(f0.y);
        af[2] = bf16rnd(f0.z); af[3] = bf16rnd(f0.w);
        af[4] = bf16rnd(f1.x); af[5] = bf16rnd(f1.y);
        af[6] = bf16rnd(f1.z); af[7] = bf16rnd(f1.w);
        short8 abf = {};
        if (m < 2) {
            float4 u0 = *(const float4*)(absrc + k0 + q * 8);
            float4 u1 = *(const float4*)(absrc + k0 + q * 8 + 4);
            abf[0] = bf16rnd(u0.x); abf[1] = bf16rnd(u0.y);
            abf[2] = bf16rnd(u0.z); abf[3] = bf16rnd(u0.w);
            abf[4] = bf16rnd(u1.x); abf[5] = bf16rnd(u1.y);
            abf[6] = bf16rnd(u1.z); abf[7] = bf16rnd(u1.w);
        }
        accab = __builtin_amdgcn_mfma_f32_16x16x32_bf16(af, abf, accab, 0, 0, 0);
        #pragma unroll
        for (int f = 0; f < 8; ++f) {
            short8 bfr = *(const short8*)(WgT + (size_t)(f * 16 + m) * C_IN + k0 + q * 8);
            accg[f] = __builtin_amdgcn_mfma_f32_16x16x32_bf16(af, bfr, accg[f], 0, 0, 0);
        }
    }
    if (wv) {
        #pragma unroll
        for (int f = 0; f < 8; ++f)
            #pragma unroll
            for (int r = 0; r < 4; ++r)
                red[wv - 1][f * 4 + r][lane] = accg[f][r];
        #pragma unroll
        for (int r = 0; r < 4; ++r)
            red[wv - 1][32 + r][lane] = accab[r];
    }
    __syncthreads();
    if (wv == 0) {
        #pragma unroll
        for (int w = 0; w < 3; ++w) {
            #pragma unroll
            for (int f = 0; f < 8; ++f)
                #pragma unroll
                for (int r = 0; r < 4; ++r)
                    accg[f][r] += red[w][f * 4 + r][lane];
            #pragma unroll
            for (int r = 0; r < 4; ++r)
                accab[r] += red[w][32 + r][lane];
        }
        #pragma unroll
        for (int f = 0; f < 8; ++f) {
            int col = f * 16 + m;
            float bgv = bg[col];
            #pragma unroll
            for (int r = 0; r < 4; ++r) {
                int row = i0 + q * 4 + r;
                g[(size_t)row * C_INT + col] = (_Float16)(accg[f][r] + bgv);
            }
        }
        if (m < 2) {
            float off = m ? scal[1] : scal[0];
            float* dst = m ? b : a;
            #pragma unroll
            for (int r = 0; r < 4; ++r) dst[i0 + q * 4 + r] = accab[r] + off;
        }
    }
}

// ---------- K3: sort (single block, verified r6/r7, unchanged) ----------

__global__ __launch_bounds__(1024) void sort_kernel(
        const float* __restrict__ b, const float* __restrict__ scal,
        unsigned* __restrict__ offs_g, unsigned short* __restrict__ perm_g,
        float* __restrict__ bsort_g) {
    __shared__ unsigned oh[NBUCK / 2];
    __shared__ unsigned cur[NBUCK / 2];
    __shared__ unsigned short ls[8192];
    __shared__ unsigned wtu[16];
    int t = threadIdx.x, lane = t & 63, wv = t >> 6;
    #pragma unroll
    for (int r = 0; r < 4; ++r) { oh[t + r * 1024] = 0u; cur[t + r * 1024] = 0u; }
    __syncthreads();
    float bmin = scal[2], inv_w = scal[3];
    int kb[8];
    #pragma unroll
    for (int r = 0; r < 8; ++r) {
        int j = t + r * 1024;
        kb[r] = bucket_of(b[j], bmin, inv_w);
        atomicAdd(&oh[kb[r] >> 1], (kb[r] & 1) ? 0x10000u : 1u);
    }
    __syncthreads();
    unsigned h[8], p = 0;
    #pragma unroll
    for (int w = 0; w < 4; ++w) {
        unsigned word = oh[t * 4 + w];
        p += word & 0xffffu;  h[w * 2]     = p;
        p += word >> 16;      h[w * 2 + 1] = p;
    }
    unsigned v = p;
    #pragma unroll
    for (int d = 1; d < 64; d <<= 1) {
        unsigned u = __shfl_up(v, d);
        if (lane >= d) v += u;
    }
    if (lane == 63) wtu[wv] = v;
    __syncthreads();
    if (t < 16) {
        unsigned w = wtu[t];
        #pragma unroll
        for (int d = 1; d < 16; d <<= 1) {
            unsigned u = __shfl_up(w, d);
            if (t >= d) w += u;
        }
        wtu[t] = w;
    }
    __syncthreads();
    unsigned base = (v - p) + (wv ? wtu[wv - 1] : 0u);
    #pragma unroll
    for (int w = 0; w < 4; ++w) {
        unsigned lo = base + h[w * 2], hi = base + h[w * 2 + 1];
        oh[t * 4 + w] = lo | (hi << 16);
        offs_g[t * 8 + w * 2 + 1] = lo;
        offs_g[t * 8 + w * 2 + 2] = hi;
    }
    if (t == 0) offs_g[0] = 0u;
    __syncthreads();
    #pragma unroll
    for (int r = 0; r < 8; ++r) {
        int j = t + r * 1024;
        int k = kb[r];
        unsigned st = 0u;
        if (k > 0) {
            unsigned word = oh[(k - 1) >> 1];
            st = ((k - 1) & 1) ? (word >> 16) : (word & 0xffffu);
        }
        unsigned old = atomicAdd(&cur[k >> 1], (k & 1) ? 0x10000u : 1u);
        unsigned pos = (k & 1) ? (old >> 16) : (old & 0xffffu);
        ls[st + pos] = (unsigned short)j;
    }
    __syncthreads();
    #pragma unroll
    for (int r = 0; r < 8; ++r) {
        int e = t + r * 1024;
        int j = ls[e];
        perm_g[e] = (unsigned short)j;
        bsort_g[e] = b[j];
    }
}

// ---------- K4: per-segment sums (SEG=128 sorted rows x 128 channels per block) ----------

__global__ __launch_bounds__(128) void segsum_kernel(
        const _Float16* __restrict__ g, const unsigned short* __restrict__ perm,
        const float* __restrict__ bsort,
        float* __restrict__ seg1, float* __restrict__ seg2) {
    __shared__ int pj[SEG];
    __shared__ float pb[SEG];
    int s = blockIdx.x, t = threadIdx.x;
    pj[t] = perm[s * SEG + t];
    pb[t] = bsort[s * SEG + t];
    __syncthreads();
    float a1 = 0.f, a2 = 0.f;
    #pragma unroll 8
    for (int e = 0; e < SEG; ++e) {
        float gv = (float)g[(size_t)pj[e] * C_INT + t];
        a1 += gv; a2 += pb[e] * gv;
    }
    seg1[s * C_INT + t] = a1;
    seg2[s * C_INT + t] = a2;
}

// ---------- K5: per-row output: seg-suffix + partial-segment + exact tail ----------
// block = row (8192 blocks), threads = channels (coalesced g-row reads).

__global__ __launch_bounds__(128) void out_kernel(
        const float* __restrict__ a, const float* __restrict__ scal,
        const _Float16* __restrict__ g,
        const unsigned* __restrict__ offs, const unsigned short* __restrict__ perm,
        const float* __restrict__ bsort,
        const float* __restrict__ seg1, const float* __restrict__ seg2,
        float* __restrict__ out, float inv_n) {
    __shared__ int pj[128];
    __shared__ float pb[128];
    int i = blockIdx.x, c = threadIdx.x;
    float ai = a[i], thr = -ai;
    float bmin = scal[2], inv_w = scal[3];
    int ki = bucket_of(thr, bmin, inv_w);
    unsigned e0 = offs[ki], e1 = offs[ki + 1];
    unsigned sstar = (e1 + SEG - 1) / SEG;     // first fully-included segment
    // segment-granular suffix (coalesced, independent loads)
    float r1 = 0.f, r2 = 0.f;
    for (unsigned s = sstar; s < NSEG; ++s) {
        r1 += seg1[s * C_INT + c];
        r2 += seg2[s * C_INT + c];
    }
    float acc = ai * r1 + r2;
    // exact range [e0, sstar*SEG): tail bucket (tested) + partial segment
    // (rows >= e1 are guaranteed b > thr; the test is true for them anyway)
    unsigned eEnd = sstar * SEG;
    for (unsigned be = e0; be < eEnd; be += 128) {
        unsigned cnt = min(128u, eEnd - be);
        if ((unsigned)c < cnt) { pj[c] = perm[be + c]; pb[c] = bsort[be + c]; }
        __syncthreads();
        for (unsigned r = 0; r < cnt; ++r) {
            float bj = pb[r];
            if (bj > thr)
                acc += (ai + bj) * (float)g[(size_t)pj[r] * C_INT + c];
        }
        __syncthreads();
    }
    out[(size_t)i * C_INT + c] = acc * inv_n;
}

// ---------- launch ----------

extern "C" void kernel_launch(void* const* d_in, const int* in_sizes, int n_in,
                              void* d_out, int out_size, void* d_ws, size_t ws_size,
                              hipStream_t stream) {
    const float* x    = (const float*)d_in[0];
    const float* Wg   = (const float*)d_in[1];
    const float* bg   = (const float*)d_in[2];
    const float* Wt   = (const float*)d_in[3];
    const float* bt   = (const float*)d_in[4];
    const float* Wp   = (const float*)d_in[5];
    const float* bp   = (const float*)d_in[6];
    const float* wcat = (const float*)d_in[7];
    float* out = (float*)d_out;
    int n = in_sizes[0] / C_IN;   // 8192

    char* w = (char*)d_ws;
    size_t off = 0;
    auto alloc = [&](size_t bytes) -> void* {
        void* p = w + off;
        off += (bytes + 255) & ~(size_t)255;
        return p;
    };
    float*          ut    = (float*)alloc(C_IN * 4);
    float*          up    = (float*)alloc(C_IN * 4);
    float*          scal  = (float*)alloc(16);
    float*          a     = (float*)alloc((size_t)n * 4);
    float*          b     = (float*)alloc((size_t)n * 4);
    unsigned*       offs  = (unsigned*)alloc((size_t)(NBUCK + 1) * 4);
    unsigned short* perm  = (unsigned short*)alloc((size_t)n * 2);
    float*          bsort = (float*)alloc((size_t)n * 4);
    _Float16*       g     = (_Float16*)alloc((size_t)n * C_INT * 2);
    unsigned short* WgT   = (unsigned short*)alloc((size_t)C_INT * C_IN * 2);
    float*          seg1  = (float*)alloc((size_t)NSEG * C_INT * 4);
    float*          seg2  = (float*)alloc((size_t)NSEG * C_INT * 4);

    prep_kernel<<<25, 256, 0, stream>>>(Wt, Wp, Wg, wcat, bt, bp, ut, up, scal, WgT);
    gemm_mfma<<<n / 16, 256, 0, stream>>>(x, WgT, bg, ut, up, scal, g, a, b);
    sort_kernel<<<1, 1024, 0, stream>>>(b, scal, offs, perm, bsort);
    segsum_kernel<<<NSEG, 128, 0, stream>>>(g, perm, bsort, seg1, seg2);
    out_kernel<<<n, 128, 0, stream>>>(a, scal, g, offs, perm, bsort, seg1, seg2,
                                      out, 1.0f / (float)n);
}

// Round 10
// 163.549 us; speedup vs baseline: 1.4988x; 1.1026x over previous
//
#include <hip/hip_runtime.h>

#define C_IN   512
#define C_INT  128
#define NBUCK  8192
#define SEG    32
#define NSEG   256   // 8192 / SEG

typedef short short8 __attribute__((ext_vector_type(8)));
typedef float floatx4 __attribute__((ext_vector_type(4)));

// ---------- helpers ----------

// Monotone (after clamp) bucket mapping; identical everywhere it is used.
__device__ __forceinline__ int bucket_of(float v, float bmin, float inv_w) {
    float fk = (v - bmin) * inv_w;
    fk = fminf(fmaxf(fk, 0.f), (float)(NBUCK - 1));
    return (int)fk;
}

// fp32 -> bf16 round-to-nearest-even
__device__ __forceinline__ short bf16rnd(float v) {
    unsigned u = __float_as_uint(v);
    return (short)((u + 0x7fffu + ((u >> 16) & 1u)) >> 16);
}

// ---------- K1: prep (verified r5, unchanged) ----------

__global__ __launch_bounds__(256) void prep_kernel(
        const float* __restrict__ Wt, const float* __restrict__ Wp,
        const float* __restrict__ Wg, const float* __restrict__ wcat,
        const float* __restrict__ bt, const float* __restrict__ bp,
        float* __restrict__ ut, float* __restrict__ up, float* __restrict__ scal,
        unsigned short* __restrict__ WgT) {
    int t = threadIdx.x, bk = blockIdx.x;
    if (bk < 16) {
        const float* W  = (bk < 8) ? Wt : Wp;
        const float* wv = wcat + ((bk < 8) ? 0 : C_INT);
        float* dst      = (bk < 8) ? ut : up;
        int k = (bk & 7) * 64 + (t >> 2);
        int q = t & 3;
        const float4* row = (const float4*)(W + (size_t)k * C_INT);
        const float4* cv4 = (const float4*)wv;
        float s = 0.f;
        #pragma unroll
        for (int i = 0; i < 8; ++i) {
            float4 a = row[q * 8 + i];
            float4 c = cv4[q * 8 + i];
            s += a.x * c.x + a.y * c.y + a.z * c.z + a.w * c.w;
        }
        s += __shfl_xor(s, 1);
        s += __shfl_xor(s, 2);
        if (q == 0) dst[k] = s;
    } else if (bk == 16) {
        float sumsq = 0.f;
        const float4* w2v = (const float4*)(wcat + C_INT);
        for (int r = 0; r < 2; ++r) {
            int k = t * 2 + r;
            const float4* row = (const float4*)(Wp + (size_t)k * C_INT);
            float d = 0.f;
            #pragma unroll
            for (int i = 0; i < 32; ++i) {
                float4 a4 = row[i]; float4 c4 = w2v[i];
                d += a4.x * c4.x + a4.y * c4.y + a4.z * c4.z + a4.w * c4.w;
            }
            sumsq += d * d;
        }
        float s1p = (t < C_INT) ? bt[t] * wcat[t] : 0.f;
        float s2p = (t < C_INT) ? bp[t] * wcat[C_INT + t] : 0.f;
        for (int off = 32; off; off >>= 1) {
            s1p   += __shfl_down(s1p, off);
            s2p   += __shfl_down(s2p, off);
            sumsq += __shfl_down(sumsq, off);
        }
        __shared__ float red[12];
        int w = t >> 6, lane = t & 63;
        if (lane == 0) { red[w] = s1p; red[4 + w] = s2p; red[8 + w] = sumsq; }
        __syncthreads();
        if (t == 0) {
            float s0 = red[0] + red[1] + red[2] + red[3];
            float s1 = red[4] + red[5] + red[6] + red[7];
            float sq = red[8] + red[9] + red[10] + red[11];
            float sigma = sqrtf(sq);
            scal[0] = s0; scal[1] = s1;
            if (sigma > 1e-20f) {
                scal[2] = s1 - 8.f * sigma;                  // bmin
                scal[3] = (float)NBUCK / (16.f * sigma);     // inv_w
            } else {
                scal[2] = s1 - 1.f; scal[3] = 0.f;           // degenerate
            }
        }
    } else {
        __shared__ float tile[64][132];
        int kb = (bk - 17) * 64;
        #pragma unroll
        for (int it = 0; it < 8; ++it) {
            int idx = it * 256 + t;
            int r = idx >> 5, c4 = idx & 31;
            *(float4*)&tile[r][c4 * 4] =
                ((const float4*)(Wg + (size_t)(kb + r) * C_INT))[c4];
        }
        __syncthreads();
        int n = t & 127, kc = (t >> 7) * 32;
        unsigned pk[16];
        #pragma unroll
        for (int i = 0; i < 16; ++i) {
            unsigned lo = (unsigned short)bf16rnd(tile[kc + 2 * i][n]);
            unsigned hi = (unsigned short)bf16rnd(tile[kc + 2 * i + 1][n]);
            pk[i] = lo | (hi << 16);
        }
        uint4* dst = (uint4*)(WgT + (size_t)n * C_IN + kb + kc);
        #pragma unroll
        for (int i2 = 0; i2 < 4; ++i2) dst[i2] = *(uint4*)&pk[i2 * 4];
    }
}

// ---------- K2: MFMA gemm, 4 waves/block K-split (verified r7, unchanged) ----------

#define RSTR 66

__global__ __launch_bounds__(256) void gemm_mfma(
        const float* __restrict__ x, const unsigned short* __restrict__ WgT,
        const float* __restrict__ bg,
        const float* __restrict__ ut, const float* __restrict__ up,
        const float* __restrict__ scal,
        _Float16* __restrict__ g, float* __restrict__ a, float* __restrict__ b) {
    __shared__ float red[3][36][RSTR];
    int tid = threadIdx.x;
    int lane = tid & 63, wv = tid >> 6;
    int i0 = blockIdx.x * 16;
    int m = lane & 15, q = lane >> 4;
    floatx4 accg[8] = {};
    floatx4 accab = {};
    const float* xrow = x + (size_t)(i0 + m) * C_IN + q * 8;
    const float* absrc = (m == 0) ? ut : up;
    #pragma unroll
    for (int ks = 0; ks < 4; ++ks) {
        int k0 = (wv * 4 + ks) * 32;
        float4 f0 = *(const float4*)(xrow + k0);
        float4 f1 = *(const float4*)(xrow + k0 + 4);
        short8 af;
        af[0] = bf16rnd(f0.x); af[1] = bf16rnd(f0.y);
        af[2] = bf16rnd(f0.z); af[3] = bf16rnd(f0.w);
        af[4] = bf16rnd(f1.x); af[5] = bf16rnd(f1.y);
        af[6] = bf16rnd(f1.z); af[7] = bf16rnd(f1.w);
        short8 abf = {};
        if (m < 2) {
            float4 u0 = *(const float4*)(absrc + k0 + q * 8);
            float4 u1 = *(const float4*)(absrc + k0 + q * 8 + 4);
            abf[0] = bf16rnd(u0.x); abf[1] = bf16rnd(u0.y);
            abf[2] = bf16rnd(u0.z); abf[3] = bf16rnd(u0.w);
            abf[4] = bf16rnd(u1.x); abf[5] = bf16rnd(u1.y);
            abf[6] = bf16rnd(u1.z); abf[7] = bf16rnd(u1.w);
        }
        accab = __builtin_amdgcn_mfma_f32_16x16x32_bf16(af, abf, accab, 0, 0, 0);
        #pragma unroll
        for (int f = 0; f < 8; ++f) {
            short8 bfr = *(const short8*)(WgT + (size_t)(f * 16 + m) * C_IN + k0 + q * 8);
            accg[f] = __builtin_amdgcn_mfma_f32_16x16x32_bf16(af, bfr, accg[f], 0, 0, 0);
        }
    }
    if (wv) {
        #pragma unroll
        for (int f = 0; f < 8; ++f)
            #pragma unroll
            for (int r = 0; r < 4; ++r)
                red[wv - 1][f * 4 + r][lane] = accg[f][r];
        #pragma unroll
        for (int r = 0; r < 4; ++r)
            red[wv - 1][32 + r][lane] = accab[r];
    }
    __syncthreads();
    if (wv == 0) {
        #pragma unroll
        for (int w = 0; w < 3; ++w) {
            #pragma unroll
            for (int f = 0; f < 8; ++f)
                #pragma unroll
                for (int r = 0; r < 4; ++r)
                    accg[f][r] += red[w][f * 4 + r][lane];
            #pragma unroll
            for (int r = 0; r < 4; ++r)
                accab[r] += red[w][32 + r][lane];
        }
        #pragma unroll
        for (int f = 0; f < 8; ++f) {
            int col = f * 16 + m;
            float bgv = bg[col];
            #pragma unroll
            for (int r = 0; r < 4; ++r) {
                int row = i0 + q * 4 + r;
                g[(size_t)row * C_INT + col] = (_Float16)(accg[f][r] + bgv);
            }
        }
        if (m < 2) {
            float off = m ? scal[1] : scal[0];
            float* dst = m ? b : a;
            #pragma unroll
            for (int r = 0; r < 4; ++r) dst[i0 + q * 4 + r] = accab[r] + off;
        }
    }
}

// ---------- K3: sort (single block, verified r6/r7, unchanged) ----------

__global__ __launch_bounds__(1024) void sort_kernel(
        const float* __restrict__ b, const float* __restrict__ scal,
        unsigned* __restrict__ offs_g, unsigned short* __restrict__ perm_g,
        float* __restrict__ bsort_g) {
    __shared__ unsigned oh[NBUCK / 2];
    __shared__ unsigned cur[NBUCK / 2];
    __shared__ unsigned short ls[8192];
    __shared__ unsigned wtu[16];
    int t = threadIdx.x, lane = t & 63, wv = t >> 6;
    #pragma unroll
    for (int r = 0; r < 4; ++r) { oh[t + r * 1024] = 0u; cur[t + r * 1024] = 0u; }
    __syncthreads();
    float bmin = scal[2], inv_w = scal[3];
    int kb[8];
    #pragma unroll
    for (int r = 0; r < 8; ++r) {
        int j = t + r * 1024;
        kb[r] = bucket_of(b[j], bmin, inv_w);
        atomicAdd(&oh[kb[r] >> 1], (kb[r] & 1) ? 0x10000u : 1u);
    }
    __syncthreads();
    unsigned h[8], p = 0;
    #pragma unroll
    for (int w = 0; w < 4; ++w) {
        unsigned word = oh[t * 4 + w];
        p += word & 0xffffu;  h[w * 2]     = p;
        p += word >> 16;      h[w * 2 + 1] = p;
    }
    unsigned v = p;
    #pragma unroll
    for (int d = 1; d < 64; d <<= 1) {
        unsigned u = __shfl_up(v, d);
        if (lane >= d) v += u;
    }
    if (lane == 63) wtu[wv] = v;
    __syncthreads();
    if (t < 16) {
        unsigned w = wtu[t];
        #pragma unroll
        for (int d = 1; d < 16; d <<= 1) {
            unsigned u = __shfl_up(w, d);
            if (t >= d) w += u;
        }
        wtu[t] = w;
    }
    __syncthreads();
    unsigned base = (v - p) + (wv ? wtu[wv - 1] : 0u);
    #pragma unroll
    for (int w = 0; w < 4; ++w) {
        unsigned lo = base + h[w * 2], hi = base + h[w * 2 + 1];
        oh[t * 4 + w] = lo | (hi << 16);
        offs_g[t * 8 + w * 2 + 1] = lo;
        offs_g[t * 8 + w * 2 + 2] = hi;
    }
    if (t == 0) offs_g[0] = 0u;
    __syncthreads();
    #pragma unroll
    for (int r = 0; r < 8; ++r) {
        int j = t + r * 1024;
        int k = kb[r];
        unsigned st = 0u;
        if (k > 0) {
            unsigned word = oh[(k - 1) >> 1];
            st = ((k - 1) & 1) ? (word >> 16) : (word & 0xffffu);
        }
        unsigned old = atomicAdd(&cur[k >> 1], (k & 1) ? 0x10000u : 1u);
        unsigned pos = (k & 1) ? (old >> 16) : (old & 0xffffu);
        ls[st + pos] = (unsigned short)j;
    }
    __syncthreads();
    #pragma unroll
    for (int r = 0; r < 8; ++r) {
        int e = t + r * 1024;
        int j = ls[e];
        perm_g[e] = (unsigned short)j;
        bsort_g[e] = b[j];
    }
}

// ---------- K4: per-segment sums (SEG=32 sorted rows x 128 channels per block) ----------

__global__ __launch_bounds__(128) void segsum_kernel(
        const _Float16* __restrict__ g, const unsigned short* __restrict__ perm,
        const float* __restrict__ bsort,
        float* __restrict__ seg1, float* __restrict__ seg2) {
    __shared__ int pj[SEG];
    __shared__ float pb[SEG];
    int s = blockIdx.x, t = threadIdx.x;
    if (t < SEG) { pj[t] = perm[s * SEG + t]; pb[t] = bsort[s * SEG + t]; }
    __syncthreads();
    float a1 = 0.f, a2 = 0.f;
    #pragma unroll
    for (int e = 0; e < SEG; ++e) {
        float gv = (float)g[(size_t)pj[e] * C_INT + t];
        a1 += gv; a2 += pb[e] * gv;
    }
    seg1[s * C_INT + t] = a1;
    seg2[s * C_INT + t] = a2;
}

// ---------- K5: segment-suffix precompute: Pseg[s] = sum_{s' >= s} seg[s'] ----------
// 256 blocks, one per segment; independent coalesced loads (pipelined).

__global__ __launch_bounds__(128) void suffix_kernel(
        const float* __restrict__ seg1, const float* __restrict__ seg2,
        float* __restrict__ Pseg1, float* __restrict__ Pseg2) {
    int s = blockIdx.x, c = threadIdx.x;
    float r1 = 0.f, r2 = 0.f;
    for (int s2 = s; s2 < NSEG; ++s2) {
        r1 += seg1[s2 * C_INT + c];
        r2 += seg2[s2 * C_INT + c];
    }
    Pseg1[s * C_INT + c] = r1;
    Pseg2[s * C_INT + c] = r2;
    if (s == 0) {
        Pseg1[(size_t)NSEG * C_INT + c] = 0.f;
        Pseg2[(size_t)NSEG * C_INT + c] = 0.f;
    }
}

// ---------- K6: per-row output: one Pseg row + small exact tail ----------
// block = row (8192 blocks), threads = channels (coalesced g-row reads).

__global__ __launch_bounds__(128) void out_kernel(
        const float* __restrict__ a, const float* __restrict__ scal,
        const _Float16* __restrict__ g,
        const unsigned* __restrict__ offs, const unsigned short* __restrict__ perm,
        const float* __restrict__ bsort,
        const float* __restrict__ Pseg1, const float* __restrict__ Pseg2,
        float* __restrict__ out, float inv_n) {
    __shared__ int pj[128];
    __shared__ float pb[128];
    int i = blockIdx.x, c = threadIdx.x;
    float ai = a[i], thr = -ai;
    float bmin = scal[2], inv_w = scal[3];
    int ki = bucket_of(thr, bmin, inv_w);
    unsigned e0 = offs[ki], e1 = offs[ki + 1];
    unsigned sstar = (e1 + SEG - 1) / SEG;     // first fully-included segment
    size_t pbase = (size_t)sstar * C_INT + c;
    float acc = ai * Pseg1[pbase] + Pseg2[pbase];
    // exact range [e0, sstar*SEG): tail bucket (tested) + partial segment
    // (rows >= e1 are guaranteed b > thr; the test is true for them anyway)
    unsigned eEnd = sstar * SEG;
    for (unsigned be = e0; be < eEnd; be += 128) {
        unsigned cnt = min(128u, eEnd - be);
        if ((unsigned)c < cnt) { pj[c] = perm[be + c]; pb[c] = bsort[be + c]; }
        __syncthreads();
        for (unsigned r = 0; r < cnt; ++r) {
            float bj = pb[r];
            if (bj > thr)
                acc += (ai + bj) * (float)g[(size_t)pj[r] * C_INT + c];
        }
        __syncthreads();
    }
    out[(size_t)i * C_INT + c] = acc * inv_n;
}

// ---------- launch ----------

extern "C" void kernel_launch(void* const* d_in, const int* in_sizes, int n_in,
                              void* d_out, int out_size, void* d_ws, size_t ws_size,
                              hipStream_t stream) {
    const float* x    = (const float*)d_in[0];
    const float* Wg   = (const float*)d_in[1];
    const float* bg   = (const float*)d_in[2];
    const float* Wt   = (const float*)d_in[3];
    const float* bt   = (const float*)d_in[4];
    const float* Wp   = (const float*)d_in[5];
    const float* bp   = (const float*)d_in[6];
    const float* wcat = (const float*)d_in[7];
    float* out = (float*)d_out;
    int n = in_sizes[0] / C_IN;   // 8192

    char* w = (char*)d_ws;
    size_t off = 0;
    auto alloc = [&](size_t bytes) -> void* {
        void* p = w + off;
        off += (bytes + 255) & ~(size_t)255;
        return p;
    };
    float*          ut    = (float*)alloc(C_IN * 4);
    float*          up    = (float*)alloc(C_IN * 4);
    float*          scal  = (float*)alloc(16);
    float*          a     = (float*)alloc((size_t)n * 4);
    float*          b     = (float*)alloc((size_t)n * 4);
    unsigned*       offs  = (unsigned*)alloc((size_t)(NBUCK + 1) * 4);
    unsigned short* perm  = (unsigned short*)alloc((size_t)n * 2);
    float*          bsort = (float*)alloc((size_t)n * 4);
    _Float16*       g     = (_Float16*)alloc((size_t)n * C_INT * 2);
    unsigned short* WgT   = (unsigned short*)alloc((size_t)C_INT * C_IN * 2);
    float*          seg1  = (float*)alloc((size_t)NSEG * C_INT * 4);
    float*          seg2  = (float*)alloc((size_t)NSEG * C_INT * 4);
    float*          Pseg1 = (float*)alloc((size_t)(NSEG + 1) * C_INT * 4);
    float*          Pseg2 = (float*)alloc((size_t)(NSEG + 1) * C_INT * 4);

    prep_kernel<<<25, 256, 0, stream>>>(Wt, Wp, Wg, wcat, bt, bp, ut, up, scal, WgT);
    gemm_mfma<<<n / 16, 256, 0, stream>>>(x, WgT, bg, ut, up, scal, g, a, b);
    sort_kernel<<<1, 1024, 0, stream>>>(b, scal, offs, perm, bsort);
    segsum_kernel<<<NSEG, 128, 0, stream>>>(g, perm, bsort, seg1, seg2);
    suffix_kernel<<<NSEG, 128, 0, stream>>>(seg1, seg2, Pseg1, Pseg2);
    out_kernel<<<n, 128, 0, stream>>>(a, scal, g, offs, perm, bsort, Pseg1, Pseg2,
                                      out, 1.0f / (float)n);
}

// Round 11
// 142.731 us; speedup vs baseline: 1.7174x; 1.1459x over previous
//
#include <hip/hip_runtime.h>

#define C_IN   512
#define C_INT  128
#define NBUCK  8192
#define SEG    32
#define NSEG   256   // 8192 / SEG

typedef short short8 __attribute__((ext_vector_type(8)));
typedef float floatx4 __attribute__((ext_vector_type(4)));

// ---------- helpers ----------

// Monotone (after clamp) bucket mapping; identical everywhere it is used.
__device__ __forceinline__ int bucket_of(float v, float bmin, float inv_w) {
    float fk = (v - bmin) * inv_w;
    fk = fminf(fmaxf(fk, 0.f), (float)(NBUCK - 1));
    return (int)fk;
}

// fp32 -> bf16 round-to-nearest-even
__device__ __forceinline__ short bf16rnd(float v) {
    unsigned u = __float_as_uint(v);
    return (short)((u + 0x7fffu + ((u >> 16) & 1u)) >> 16);
}

// ---------- K1: prep (verified r5, unchanged) ----------

__global__ __launch_bounds__(256) void prep_kernel(
        const float* __restrict__ Wt, const float* __restrict__ Wp,
        const float* __restrict__ Wg, const float* __restrict__ wcat,
        const float* __restrict__ bt, const float* __restrict__ bp,
        float* __restrict__ ut, float* __restrict__ up, float* __restrict__ scal,
        unsigned short* __restrict__ WgT) {
    int t = threadIdx.x, bk = blockIdx.x;
    if (bk < 16) {
        const float* W  = (bk < 8) ? Wt : Wp;
        const float* wv = wcat + ((bk < 8) ? 0 : C_INT);
        float* dst      = (bk < 8) ? ut : up;
        int k = (bk & 7) * 64 + (t >> 2);
        int q = t & 3;
        const float4* row = (const float4*)(W + (size_t)k * C_INT);
        const float4* cv4 = (const float4*)wv;
        float s = 0.f;
        #pragma unroll
        for (int i = 0; i < 8; ++i) {
            float4 a = row[q * 8 + i];
            float4 c = cv4[q * 8 + i];
            s += a.x * c.x + a.y * c.y + a.z * c.z + a.w * c.w;
        }
        s += __shfl_xor(s, 1);
        s += __shfl_xor(s, 2);
        if (q == 0) dst[k] = s;
    } else if (bk == 16) {
        float s1p = (t < C_INT) ? bt[t] * wcat[t] : 0.f;
        float s2p = (t < C_INT) ? bp[t] * wcat[C_INT + t] : 0.f;
        for (int off = 32; off; off >>= 1) {
            s1p += __shfl_down(s1p, off);
            s2p += __shfl_down(s2p, off);
        }
        __shared__ float red[8];
        int w = t >> 6, lane = t & 63;
        if (lane == 0) { red[w] = s1p; red[4 + w] = s2p; }
        __syncthreads();
        if (t == 0) {
            scal[0] = red[0] + red[1] + red[2] + red[3];
            scal[1] = red[4] + red[5] + red[6] + red[7];
        }
    } else {
        __shared__ float tile[64][132];
        int kb = (bk - 17) * 64;
        #pragma unroll
        for (int it = 0; it < 8; ++it) {
            int idx = it * 256 + t;
            int r = idx >> 5, c4 = idx & 31;
            *(float4*)&tile[r][c4 * 4] =
                ((const float4*)(Wg + (size_t)(kb + r) * C_INT))[c4];
        }
        __syncthreads();
        int n = t & 127, kc = (t >> 7) * 32;
        unsigned pk[16];
        #pragma unroll
        for (int i = 0; i < 16; ++i) {
            unsigned lo = (unsigned short)bf16rnd(tile[kc + 2 * i][n]);
            unsigned hi = (unsigned short)bf16rnd(tile[kc + 2 * i + 1][n]);
            pk[i] = lo | (hi << 16);
        }
        uint4* dst = (uint4*)(WgT + (size_t)n * C_IN + kb + kc);
        #pragma unroll
        for (int i2 = 0; i2 < 4; ++i2) dst[i2] = *(uint4*)&pk[i2 * 4];
    }
}

// ---------- K2: MFMA gemm, col-split: 1024 blocks x (16 rows x 64 cols), 4-wave K-split ----------
// 4 blocks/CU resident -> 16 waves/CU (2x r7's occupancy).

#define RSTR 66

__global__ __launch_bounds__(256) void gemm_mfma(
        const float* __restrict__ x, const unsigned short* __restrict__ WgT,
        const float* __restrict__ bg,
        const float* __restrict__ ut, const float* __restrict__ up,
        const float* __restrict__ scal,
        _Float16* __restrict__ g, float* __restrict__ a, float* __restrict__ b) {
    __shared__ float red[3][20][RSTR];
    int tid = threadIdx.x;
    int lane = tid & 63, wv = tid >> 6;
    int bx = blockIdx.x;
    int i0 = (bx >> 1) * 16;
    int cg = bx & 1;                 // column group: cols cg*64 .. cg*64+63
    int m = lane & 15, q = lane >> 4;
    floatx4 accg[4] = {};
    floatx4 accab = {};
    const float* xrow = x + (size_t)(i0 + m) * C_IN + q * 8;
    const float* absrc = (m == 0) ? ut : up;
    #pragma unroll
    for (int ks = 0; ks < 4; ++ks) {
        int k0 = (wv * 4 + ks) * 32;
        float4 f0 = *(const float4*)(xrow + k0);
        float4 f1 = *(const float4*)(xrow + k0 + 4);
        short8 af;
        af[0] = bf16rnd(f0.x); af[1] = bf16rnd(f0.y);
        af[2] = bf16rnd(f0.z); af[3] = bf16rnd(f0.w);
        af[4] = bf16rnd(f1.x); af[5] = bf16rnd(f1.y);
        af[6] = bf16rnd(f1.z); af[7] = bf16rnd(f1.w);
        if (cg == 0) {
            short8 abf = {};
            if (m < 2) {
                float4 u0 = *(const float4*)(absrc + k0 + q * 8);
                float4 u1 = *(const float4*)(absrc + k0 + q * 8 + 4);
                abf[0] = bf16rnd(u0.x); abf[1] = bf16rnd(u0.y);
                abf[2] = bf16rnd(u0.z); abf[3] = bf16rnd(u0.w);
                abf[4] = bf16rnd(u1.x); abf[5] = bf16rnd(u1.y);
                abf[6] = bf16rnd(u1.z); abf[7] = bf16rnd(u1.w);
            }
            accab = __builtin_amdgcn_mfma_f32_16x16x32_bf16(af, abf, accab, 0, 0, 0);
        }
        #pragma unroll
        for (int f = 0; f < 4; ++f) {
            short8 bfr = *(const short8*)(WgT + (size_t)(cg * 64 + f * 16 + m) * C_IN + k0 + q * 8);
            accg[f] = __builtin_amdgcn_mfma_f32_16x16x32_bf16(af, bfr, accg[f], 0, 0, 0);
        }
    }
    if (wv) {
        #pragma unroll
        for (int f = 0; f < 4; ++f)
            #pragma unroll
            for (int r = 0; r < 4; ++r)
                red[wv - 1][f * 4 + r][lane] = accg[f][r];
        #pragma unroll
        for (int r = 0; r < 4; ++r)
            red[wv - 1][16 + r][lane] = accab[r];
    }
    __syncthreads();
    if (wv == 0) {
        #pragma unroll
        for (int w = 0; w < 3; ++w) {
            #pragma unroll
            for (int f = 0; f < 4; ++f)
                #pragma unroll
                for (int r = 0; r < 4; ++r)
                    accg[f][r] += red[w][f * 4 + r][lane];
            #pragma unroll
            for (int r = 0; r < 4; ++r)
                accab[r] += red[w][16 + r][lane];
        }
        // epilogue: C layout col = lane&15, row = q*4 + reg
        #pragma unroll
        for (int f = 0; f < 4; ++f) {
            int col = cg * 64 + f * 16 + m;
            float bgv = bg[col];
            #pragma unroll
            for (int r = 0; r < 4; ++r) {
                int row = i0 + q * 4 + r;
                g[(size_t)row * C_INT + col] = (_Float16)(accg[f][r] + bgv);
            }
        }
        if (cg == 0 && m < 2) {
            float off = m ? scal[1] : scal[0];
            float* dst = m ? b : a;
            #pragma unroll
            for (int r = 0; r < 4; ++r) dst[i0 + q * 4 + r] = accab[r] + off;
        }
    }
}

// ---------- K3: sort (single block) + exact min/max bucket range ----------

__global__ __launch_bounds__(1024) void sort_kernel(
        const float* __restrict__ b, float* __restrict__ scal,
        unsigned* __restrict__ offs_g, unsigned short* __restrict__ perm_g,
        float* __restrict__ bsort_g) {
    __shared__ unsigned oh[NBUCK / 2];
    __shared__ unsigned cur[NBUCK / 2];
    __shared__ unsigned short ls[8192];
    __shared__ unsigned wtu[16];
    __shared__ float smn[16], smx[16], sbp[2];
    int t = threadIdx.x, lane = t & 63, wv = t >> 6;
    #pragma unroll
    for (int r = 0; r < 4; ++r) { oh[t + r * 1024] = 0u; cur[t + r * 1024] = 0u; }
    // load b, exact min/max
    float bv[8];
    float mn = 1e30f, mx = -1e30f;
    #pragma unroll
    for (int r = 0; r < 8; ++r) {
        bv[r] = b[t + r * 1024];
        mn = fminf(mn, bv[r]); mx = fmaxf(mx, bv[r]);
    }
    for (int off = 32; off; off >>= 1) {
        mn = fminf(mn, __shfl_down(mn, off));
        mx = fmaxf(mx, __shfl_down(mx, off));
    }
    if (lane == 0) { smn[wv] = mn; smx[wv] = mx; }
    __syncthreads();
    if (t == 0) {
        float gmn = smn[0], gmx = smx[0];
        #pragma unroll
        for (int i = 1; i < 16; ++i) {
            gmn = fminf(gmn, smn[i]); gmx = fmaxf(gmx, smx[i]);
        }
        float range = gmx - gmn;
        float iw = (range > 1e-30f) ? (float)NBUCK / range : 0.f;
        sbp[0] = gmn; sbp[1] = iw;
        scal[4] = gmn; scal[5] = iw;    // publish for out_kernel
    }
    __syncthreads();
    float bmin = sbp[0], inv_w = sbp[1];
    int kb[8];
    #pragma unroll
    for (int r = 0; r < 8; ++r) {
        kb[r] = bucket_of(bv[r], bmin, inv_w);
        atomicAdd(&oh[kb[r] >> 1], (kb[r] & 1) ? 0x10000u : 1u);
    }
    __syncthreads();
    unsigned h[8], p = 0;
    #pragma unroll
    for (int w = 0; w < 4; ++w) {
        unsigned word = oh[t * 4 + w];
        p += word & 0xffffu;  h[w * 2]     = p;
        p += word >> 16;      h[w * 2 + 1] = p;
    }
    unsigned v = p;
    #pragma unroll
    for (int d = 1; d < 64; d <<= 1) {
        unsigned u = __shfl_up(v, d);
        if (lane >= d) v += u;
    }
    if (lane == 63) wtu[wv] = v;
    __syncthreads();
    if (t < 16) {
        unsigned w = wtu[t];
        #pragma unroll
        for (int d = 1; d < 16; d <<= 1) {
            unsigned u = __shfl_up(w, d);
            if (t >= d) w += u;
        }
        wtu[t] = w;
    }
    __syncthreads();
    unsigned base = (v - p) + (wv ? wtu[wv - 1] : 0u);
    #pragma unroll
    for (int w = 0; w < 4; ++w) {
        unsigned lo = base + h[w * 2], hi = base + h[w * 2 + 1];
        oh[t * 4 + w] = lo | (hi << 16);
        offs_g[t * 8 + w * 2 + 1] = lo;
        offs_g[t * 8 + w * 2 + 2] = hi;
    }
    if (t == 0) offs_g[0] = 0u;
    __syncthreads();
    #pragma unroll
    for (int r = 0; r < 8; ++r) {
        int j = t + r * 1024;
        int k = kb[r];
        unsigned st = 0u;
        if (k > 0) {
            unsigned word = oh[(k - 1) >> 1];
            st = ((k - 1) & 1) ? (word >> 16) : (word & 0xffffu);
        }
        unsigned old = atomicAdd(&cur[k >> 1], (k & 1) ? 0x10000u : 1u);
        unsigned pos = (k & 1) ? (old >> 16) : (old & 0xffffu);
        ls[st + pos] = (unsigned short)j;
    }
    __syncthreads();
    #pragma unroll
    for (int r = 0; r < 8; ++r) {
        int e = t + r * 1024;
        int j = ls[e];
        perm_g[e] = (unsigned short)j;
        bsort_g[e] = b[j];
    }
}

// ---------- K4: per-segment sums (SEG=32, verified r7) ----------

__global__ __launch_bounds__(128) void segsum_kernel(
        const _Float16* __restrict__ g, const unsigned short* __restrict__ perm,
        const float* __restrict__ bsort,
        float* __restrict__ seg1, float* __restrict__ seg2) {
    __shared__ int pj[SEG];
    __shared__ float pb[SEG];
    int s = blockIdx.x, t = threadIdx.x;
    if (t < SEG) { pj[t] = perm[s * SEG + t]; pb[t] = bsort[s * SEG + t]; }
    __syncthreads();
    float a1 = 0.f, a2 = 0.f;
    #pragma unroll
    for (int e = 0; e < SEG; ++e) {
        float gv = (float)g[(size_t)pj[e] * C_INT + t];
        a1 += gv; a2 += pb[e] * gv;
    }
    seg1[s * C_INT + t] = a1;
    seg2[s * C_INT + t] = a2;
}

// ---------- K5: expand to row-granular suffix sums Pr1/Pr2 (verified r7) ----------

__global__ __launch_bounds__(128) void expand_kernel(
        const _Float16* __restrict__ g, const unsigned short* __restrict__ perm,
        const float* __restrict__ bsort,
        const float* __restrict__ seg1, const float* __restrict__ seg2,
        float* __restrict__ Pr1, float* __restrict__ Pr2) {
    __shared__ int pj[SEG];
    __shared__ float pb[SEG];
    int s = blockIdx.x, t = threadIdx.x;
    if (t < SEG) { pj[t] = perm[s * SEG + t]; pb[t] = bsort[s * SEG + t]; }
    __syncthreads();
    float r1 = 0.f, r2 = 0.f;
    for (int s2 = s + 1; s2 < NSEG; ++s2) {
        r1 += seg1[s2 * C_INT + t];
        r2 += seg2[s2 * C_INT + t];
    }
    #pragma unroll
    for (int e = SEG - 1; e >= 0; --e) {
        float gv = (float)g[(size_t)pj[e] * C_INT + t];
        r1 += gv; r2 += pb[e] * gv;
        size_t idx = (size_t)(s * SEG + e) * C_INT + t;
        Pr1[idx] = r1; Pr2[idx] = r2;
    }
    if (s == NSEG - 1) {
        Pr1[(size_t)8192 * C_INT + t] = 0.f;
        Pr2[(size_t)8192 * C_INT + t] = 0.f;
    }
}

// ---------- K6: per-row output: Pr lookup + ~1-row exact tail (verified r7) ----------

__global__ __launch_bounds__(128) void out_kernel(
        const float* __restrict__ a, const float* __restrict__ scal,
        const _Float16* __restrict__ g,
        const unsigned* __restrict__ offs, const unsigned short* __restrict__ perm,
        const float* __restrict__ bsort,
        const float* __restrict__ Pr1, const float* __restrict__ Pr2,
        float* __restrict__ out, float inv_n) {
    __shared__ int pj[128];
    __shared__ float pb[128];
    int i = blockIdx.x, c = threadIdx.x;
    float ai = a[i], thr = -ai;
    float bmin = scal[4], inv_w = scal[5];
    int ki = bucket_of(thr, bmin, inv_w);
    unsigned e0 = offs[ki], e1 = offs[ki + 1];
    size_t base = (size_t)e1 * C_INT + c;
    float acc = ai * Pr1[base] + Pr2[base];
    for (unsigned be = e0; be < e1; be += 128) {
        unsigned cnt = min(128u, e1 - be);
        if ((unsigned)c < cnt) { pj[c] = perm[be + c]; pb[c] = bsort[be + c]; }
        __syncthreads();
        for (unsigned r = 0; r < cnt; ++r) {
            float bj = pb[r];
            if (bj > thr)
                acc += (ai + bj) * (float)g[(size_t)pj[r] * C_INT + c];
        }
        __syncthreads();
    }
    out[(size_t)i * C_INT + c] = acc * inv_n;
}

// ---------- launch ----------

extern "C" void kernel_launch(void* const* d_in, const int* in_sizes, int n_in,
                              void* d_out, int out_size, void* d_ws, size_t ws_size,
                              hipStream_t stream) {
    const float* x    = (const float*)d_in[0];
    const float* Wg   = (const float*)d_in[1];
    const float* bg   = (const float*)d_in[2];
    const float* Wt   = (const float*)d_in[3];
    const float* bt   = (const float*)d_in[4];
    const float* Wp   = (const float*)d_in[5];
    const float* bp   = (const float*)d_in[6];
    const float* wcat = (const float*)d_in[7];
    float* out = (float*)d_out;
    int n = in_sizes[0] / C_IN;   // 8192

    char* w = (char*)d_ws;
    size_t off = 0;
    auto alloc = [&](size_t bytes) -> void* {
        void* p = w + off;
        off += (bytes + 255) & ~(size_t)255;
        return p;
    };
    float*          ut    = (float*)alloc(C_IN * 4);
    float*          up    = (float*)alloc(C_IN * 4);
    float*          scal  = (float*)alloc(32);
    float*          a     = (float*)alloc((size_t)n * 4);
    float*          b     = (float*)alloc((size_t)n * 4);
    unsigned*       offs  = (unsigned*)alloc((size_t)(NBUCK + 1) * 4);
    unsigned short* perm  = (unsigned short*)alloc((size_t)n * 2);
    float*          bsort = (float*)alloc((size_t)n * 4);
    _Float16*       g     = (_Float16*)alloc((size_t)n * C_INT * 2);
    unsigned short* WgT   = (unsigned short*)alloc((size_t)C_INT * C_IN * 2);
    float*          seg1  = (float*)alloc((size_t)NSEG * C_INT * 4);
    float*          seg2  = (float*)alloc((size_t)NSEG * C_INT * 4);
    float*          Pr1   = (float*)alloc((size_t)(n + 1) * C_INT * 4);
    float*          Pr2   = (float*)alloc((size_t)(n + 1) * C_INT * 4);

    prep_kernel<<<25, 256, 0, stream>>>(Wt, Wp, Wg, wcat, bt, bp, ut, up, scal, WgT);
    gemm_mfma<<<n / 8, 256, 0, stream>>>(x, WgT, bg, ut, up, scal, g, a, b);
    sort_kernel<<<1, 1024, 0, stream>>>(b, scal, offs, perm, bsort);
    segsum_kernel<<<NSEG, 128, 0, stream>>>(g, perm, bsort, seg1, seg2);
    expand_kernel<<<NSEG, 128, 0, stream>>>(g, perm, bsort, seg1, seg2, Pr1, Pr2);
    out_kernel<<<n, 128, 0, stream>>>(a, scal, g, offs, perm, bsort, Pr1, Pr2,
                                      out, 1.0f / (float)n);
}